// Round 2
// baseline (134.776 us; speedup 1.0000x reference)
//
#include <hip/hip_runtime.h>
#include <math.h>

#define NN 512
#define MM 31
#define TT 32            // M+1 tokens per node
#define EE 64            // INP = EMB = ATT
#define NREL 200
#define SELF_LOOP 200
#define LCAP 1024        // per-relation bucket capacity (mean 82, 100-sigma safe)

// ---------------------------------------------------------------------------
// prep: curr = h @ W_self  (per node), and k[n][0] = curr @ K[200] (dense,
// since kx index of token 0 is ALWAYS the self-loop relation 200).
// ---------------------------------------------------------------------------
__global__ __launch_bounds__(64) void prep_kernel(
    const float* __restrict__ h, const float* __restrict__ W_self,
    const float* __restrict__ K,
    float* __restrict__ curr_all, float* __restrict__ k_all)
{
    const int n = blockIdx.x, a = threadIdx.x;
    __shared__ float c_s[EE];
    const float* hrow = h + n * EE;
    float acc = 0.f;
#pragma unroll 8
    for (int e = 0; e < EE; ++e)
        acc = fmaf(hrow[e], W_self[e * EE + a], acc);
    curr_all[n * EE + a] = acc;
    c_s[a] = acc;
    __syncthreads();
    const float* K200 = K + (size_t)SELF_LOOP * EE * EE;
    float k0 = 0.f;
#pragma unroll 8
    for (int e = 0; e < EE; ++e)
        k0 = fmaf(c_s[e], K200[e * EE + a], k0);
    k_all[(size_t)n * TT * EE + a] = k0;
}

// ---------------------------------------------------------------------------
// proj: one block per relation r. Build token lists by scanning the label
// arrays (they ARE the bucket keys), stage W in LDS once, grouped matvecs.
// Register tiling: thread = 4 tokens x 4 outputs (float4), VALU-bound.
// ---------------------------------------------------------------------------
__global__ __launch_bounds__(256) void proj_kernel(
    const float* __restrict__ curr_all, const float* __restrict__ msg,
    const int* __restrict__ msg_type, const int* __restrict__ r_label_node,
    const int* __restrict__ r_label_msg,
    const float* __restrict__ Q, const float* __restrict__ K,
    const float* __restrict__ V,
    float* __restrict__ q_all, float* __restrict__ k_all,
    float* __restrict__ v_all)
{
    const int r   = blockIdx.x;
    const int tid = threadIdx.x;

    __shared__ float wA[4096];       // Q[r] in phase A, K[r] in phase B
    __shared__ float wB[4096];       // V[r]
    __shared__ float x_s[64][68];    // 64-token x tile, padded stride
    __shared__ int   list_q[LCAP], list_k[LCAP];
    __shared__ int   nq_s, nk_s;

    if (tid == 0) { nq_s = 0; nk_s = 0; }
    __syncthreads();

    // ---- build buckets (order within bucket irrelevant) ----
    for (int i = tid; i < NN; i += 256)
        if (r_label_node[i] == r) {
            int p = atomicAdd(&nq_s, 1);
            if (p < LCAP) list_q[p] = i * TT;          // token (n,0)
        }
    for (int j = tid; j < NN * MM; j += 256) {
        int rl = r_label_msg[j];
        int mt = msg_type[j];
        if (rl == r) {
            int n = j / MM, m = j - n * MM;
            int p = atomicAdd(&nq_s, 1);
            if (p < LCAP) list_q[p] = n * TT + m + 1;
        }
        if (mt == r) {
            int n = j / MM, m = j - n * MM;
            int p = atomicAdd(&nk_s, 1);
            if (p < LCAP) list_k[p] = n * TT + m + 1;
        }
    }

    // ---- stage Q[r], V[r] ----
    {
        const float4* Qs = (const float4*)(Q + (size_t)r * EE * EE);
        const float4* Vs = (const float4*)(V + (size_t)r * EE * EE);
        for (int i = tid; i < 1024; i += 256) {
            ((float4*)wA)[i] = Qs[i];
            ((float4*)wB)[i] = Vs[i];
        }
    }
    __syncthreads();

    const int nq = min(nq_s, LCAP);
    const int nk = min(nk_s, LCAP);
    const int oc  = tid & 15;        // output float4 column
    const int tr4 = (tid >> 4) * 4;  // first of 4 token rows

    // ---- phase A: q and v over list_q ----
    for (int base = 0; base < nq; base += 64) {
        {   // stage x tile: thread -> token row tid>>2, 4 float4 cols
            int tl = tid >> 2;
            int idx = base + tl;
            if (idx < nq) {
                int token = list_q[idx];
                int n = token >> 5, t = token & 31;
                const float4* src = (t == 0)
                    ? (const float4*)(curr_all + n * EE)
                    : (const float4*)(msg + ((size_t)n * MM + (t - 1)) * EE);
#pragma unroll
                for (int p = 0; p < 4; ++p) {
                    int fc = (tid & 3) + 4 * p;
                    ((float4*)&x_s[tl][0])[fc] = src[fc];
                }
            }
        }
        __syncthreads();

        float4 aq[4], av[4];
#pragma unroll
        for (int i = 0; i < 4; ++i) { aq[i] = make_float4(0,0,0,0); av[i] = make_float4(0,0,0,0); }

#pragma unroll 4
        for (int e = 0; e < EE; ++e) {
            float4 wq4 = ((const float4*)wA)[e * 16 + oc];
            float4 wv4 = ((const float4*)wB)[e * 16 + oc];
            float x0 = x_s[tr4 + 0][e];
            float x1 = x_s[tr4 + 1][e];
            float x2 = x_s[tr4 + 2][e];
            float x3 = x_s[tr4 + 3][e];
            aq[0].x = fmaf(x0, wq4.x, aq[0].x); aq[0].y = fmaf(x0, wq4.y, aq[0].y);
            aq[0].z = fmaf(x0, wq4.z, aq[0].z); aq[0].w = fmaf(x0, wq4.w, aq[0].w);
            aq[1].x = fmaf(x1, wq4.x, aq[1].x); aq[1].y = fmaf(x1, wq4.y, aq[1].y);
            aq[1].z = fmaf(x1, wq4.z, aq[1].z); aq[1].w = fmaf(x1, wq4.w, aq[1].w);
            aq[2].x = fmaf(x2, wq4.x, aq[2].x); aq[2].y = fmaf(x2, wq4.y, aq[2].y);
            aq[2].z = fmaf(x2, wq4.z, aq[2].z); aq[2].w = fmaf(x2, wq4.w, aq[2].w);
            aq[3].x = fmaf(x3, wq4.x, aq[3].x); aq[3].y = fmaf(x3, wq4.y, aq[3].y);
            aq[3].z = fmaf(x3, wq4.z, aq[3].z); aq[3].w = fmaf(x3, wq4.w, aq[3].w);
            av[0].x = fmaf(x0, wv4.x, av[0].x); av[0].y = fmaf(x0, wv4.y, av[0].y);
            av[0].z = fmaf(x0, wv4.z, av[0].z); av[0].w = fmaf(x0, wv4.w, av[0].w);
            av[1].x = fmaf(x1, wv4.x, av[1].x); av[1].y = fmaf(x1, wv4.y, av[1].y);
            av[1].z = fmaf(x1, wv4.z, av[1].z); av[1].w = fmaf(x1, wv4.w, av[1].w);
            av[2].x = fmaf(x2, wv4.x, av[2].x); av[2].y = fmaf(x2, wv4.y, av[2].y);
            av[2].z = fmaf(x2, wv4.z, av[2].z); av[2].w = fmaf(x2, wv4.w, av[2].w);
            av[3].x = fmaf(x3, wv4.x, av[3].x); av[3].y = fmaf(x3, wv4.y, av[3].y);
            av[3].z = fmaf(x3, wv4.z, av[3].z); av[3].w = fmaf(x3, wv4.w, av[3].w);
        }

#pragma unroll
        for (int i = 0; i < 4; ++i) {
            int idx = base + tr4 + i;
            if (idx < nq) {
                int token = list_q[idx];
                ((float4*)(q_all + (size_t)token * EE))[oc] = aq[i];
                ((float4*)(v_all + (size_t)token * EE))[oc] = av[i];
            }
        }
        __syncthreads();
    }

    // ---- phase B: k over list_k (reuse wA for K[r]) ----
    {
        const float4* Ks = (const float4*)(K + (size_t)r * EE * EE);
        for (int i = tid; i < 1024; i += 256)
            ((float4*)wA)[i] = Ks[i];
    }
    __syncthreads();

    for (int base = 0; base < nk; base += 64) {
        {
            int tl = tid >> 2;
            int idx = base + tl;
            if (idx < nk) {
                int token = list_k[idx];
                int n = token >> 5, t = token & 31;   // t >= 1 always here
                const float4* src = (const float4*)(msg + ((size_t)n * MM + (t - 1)) * EE);
#pragma unroll
                for (int p = 0; p < 4; ++p) {
                    int fc = (tid & 3) + 4 * p;
                    ((float4*)&x_s[tl][0])[fc] = src[fc];
                }
            }
        }
        __syncthreads();

        float4 ak[4];
#pragma unroll
        for (int i = 0; i < 4; ++i) ak[i] = make_float4(0,0,0,0);

#pragma unroll 4
        for (int e = 0; e < EE; ++e) {
            float4 wk4 = ((const float4*)wA)[e * 16 + oc];
            float x0 = x_s[tr4 + 0][e];
            float x1 = x_s[tr4 + 1][e];
            float x2 = x_s[tr4 + 2][e];
            float x3 = x_s[tr4 + 3][e];
            ak[0].x = fmaf(x0, wk4.x, ak[0].x); ak[0].y = fmaf(x0, wk4.y, ak[0].y);
            ak[0].z = fmaf(x0, wk4.z, ak[0].z); ak[0].w = fmaf(x0, wk4.w, ak[0].w);
            ak[1].x = fmaf(x1, wk4.x, ak[1].x); ak[1].y = fmaf(x1, wk4.y, ak[1].y);
            ak[1].z = fmaf(x1, wk4.z, ak[1].z); ak[1].w = fmaf(x1, wk4.w, ak[1].w);
            ak[2].x = fmaf(x2, wk4.x, ak[2].x); ak[2].y = fmaf(x2, wk4.y, ak[2].y);
            ak[2].z = fmaf(x2, wk4.z, ak[2].z); ak[2].w = fmaf(x2, wk4.w, ak[2].w);
            ak[3].x = fmaf(x3, wk4.x, ak[3].x); ak[3].y = fmaf(x3, wk4.y, ak[3].y);
            ak[3].z = fmaf(x3, wk4.z, ak[3].z); ak[3].w = fmaf(x3, wk4.w, ak[3].w);
        }

#pragma unroll
        for (int i = 0; i < 4; ++i) {
            int idx = base + tr4 + i;
            if (idx < nk) {
                int token = list_k[idx];
                ((float4*)(k_all + (size_t)token * EE))[oc] = ak[i];
            }
        }
        __syncthreads();
    }
}

// ---------------------------------------------------------------------------
// attn: one block per node; q/k/v are contiguous [32][64] rows now.
// ---------------------------------------------------------------------------
__global__ __launch_bounds__(256) void attn_kernel(
    const float* __restrict__ q_all, const float* __restrict__ k_all,
    const float* __restrict__ v_all, const float* __restrict__ ffn_w,
    const float* __restrict__ ffn_b, float* __restrict__ out)
{
    const int n = blockIdx.x, tid = threadIdx.x;
    __shared__ float q_s[TT][68], k_s[TT][68], v_s[TT][68];
    __shared__ float s_s[TT][TT + 1];
    __shared__ float att0[TT];
    __shared__ float pooled[EE];

    {
        const float4* qg = (const float4*)(q_all + (size_t)n * TT * EE);
        const float4* kg = (const float4*)(k_all + (size_t)n * TT * EE);
        const float4* vg = (const float4*)(v_all + (size_t)n * TT * EE);
        for (int i = tid; i < TT * EE / 4; i += 256) {
            int row = i >> 4, col = i & 15;
            ((float4*)&q_s[row][0])[col] = qg[i];
            ((float4*)&k_s[row][0])[col] = kg[i];
            ((float4*)&v_s[row][0])[col] = vg[i];
        }
    }
    __syncthreads();

    {   // scores s[qi][ki] = dot(q[qi],k[ki]) / 8
        const int ki = tid & 31;
        for (int qi = tid >> 5; qi < TT; qi += 8) {
            const float4* qp = (const float4*)&q_s[qi][0];
            const float4* kp = (const float4*)&k_s[ki][0];
            float acc = 0.f;
            for (int e4 = 0; e4 < EE / 4; ++e4) {
                float4 a = qp[e4], b = kp[e4];
                acc += a.x * b.x + a.y * b.y + a.z * b.z + a.w * b.w;
            }
            s_s[qi][ki] = acc * 0.125f;
        }
    }
    __syncthreads();

    // softmax over the QUERY axis per column; only row 0 of att needed
    if (tid < TT) {
        float mx = -INFINITY;
        for (int qi = 0; qi < TT; ++qi) mx = fmaxf(mx, s_s[qi][tid]);
        float sum = 0.f;
        for (int qi = 0; qi < TT; ++qi) sum += __expf(s_s[qi][tid] - mx);
        att0[tid] = __expf(s_s[0][tid] - mx) / sum;
    }
    __syncthreads();

    if (tid < EE) {
        float acc = 0.f;
        for (int ki = 0; ki < TT; ++ki)
            acc = fmaf(att0[ki], v_s[ki][tid], acc);
        pooled[tid] = acc;
    }
    __syncthreads();

    if (tid < EE) {
        float acc = ffn_b[tid];
        for (int a = 0; a < EE; ++a)
            acc = fmaf(pooled[a], ffn_w[a * EE + tid], acc);
        out[n * EE + tid] = acc;
    }
}

extern "C" void kernel_launch(void* const* d_in, const int* in_sizes, int n_in,
                              void* d_out, int out_size, void* d_ws, size_t ws_size,
                              hipStream_t stream) {
    const float* h            = (const float*)d_in[0];
    const float* msg          = (const float*)d_in[1];
    const int*   msg_type     = (const int*)  d_in[2];
    const int*   r_label_node = (const int*)  d_in[3];
    const int*   r_label_msg  = (const int*)  d_in[4];
    const float* W_self       = (const float*)d_in[5];
    const float* Q            = (const float*)d_in[6];
    const float* K            = (const float*)d_in[7];
    const float* V            = (const float*)d_in[8];
    const float* ffn_w        = (const float*)d_in[9];
    const float* ffn_b        = (const float*)d_in[10];
    float*       out          = (float*)d_out;

    // workspace: curr_all [512*64] | q_all | k_all | v_all  (each 512*32*64 f32)
    float* curr_all = (float*)d_ws;
    float* q_all = curr_all + NN * EE;
    float* k_all = q_all + (size_t)NN * TT * EE;
    float* v_all = k_all + (size_t)NN * TT * EE;

    prep_kernel<<<NN, 64, 0, stream>>>(h, W_self, K, curr_all, k_all);
    proj_kernel<<<NREL, 256, 0, stream>>>(curr_all, msg, msg_type, r_label_node,
                                          r_label_msg, Q, K, V,
                                          q_all, k_all, v_all);
    attn_kernel<<<NN, 256, 0, stream>>>(q_all, k_all, v_all, ffn_w, ffn_b, out);
}

// Round 3
// 127.861 us; speedup vs baseline: 1.0541x; 1.0541x over previous
//
#include <hip/hip_runtime.h>
#include <math.h>

#define NN 512
#define MM 31
#define TT 32            // M+1 tokens per node
#define EE 64            // INP = EMB = ATT
#define NREL 200
#define SELF_LOOP 200
#define LCAP 1024        // per-relation bucket capacity (mean ~82)
#define WSTR 72          // bf16 LDS row stride (16B-aligned, 2-way banks max)

typedef short  short8 __attribute__((ext_vector_type(8)));
typedef float  f32x4  __attribute__((ext_vector_type(4)));

__device__ __forceinline__ unsigned short f2bf(float f) {
    union { float f; unsigned int u; } a; a.f = f;
    unsigned int r = a.u + 0x7FFFu + ((a.u >> 16) & 1u);   // RNE
    return (unsigned short)(r >> 16);
}

// ---------------------------------------------------------------------------
// prep: curr = h @ W_self (per node); k[n][0] = curr @ K[200] (self-loop,
// kx index of token 0 is always relation 200). f32 throughout.
// ---------------------------------------------------------------------------
__global__ __launch_bounds__(64) void prep_kernel(
    const float* __restrict__ h, const float* __restrict__ W_self,
    const float* __restrict__ K,
    float* __restrict__ curr_all, float* __restrict__ k_all)
{
    const int n = blockIdx.x, a = threadIdx.x;
    __shared__ float c_s[EE];
    const float* hrow = h + n * EE;
    float acc = 0.f;
#pragma unroll 8
    for (int e = 0; e < EE; ++e)
        acc = fmaf(hrow[e], W_self[e * EE + a], acc);
    curr_all[n * EE + a] = acc;
    c_s[a] = acc;
    __syncthreads();
    const float* K200 = K + (size_t)SELF_LOOP * EE * EE;
    float k0 = 0.f;
#pragma unroll 8
    for (int e = 0; e < EE; ++e)
        k0 = fmaf(c_s[e], K200[e * EE + a], k0);
    k_all[(size_t)n * TT * EE + a] = k0;
}

// ---------------------------------------------------------------------------
// proj: one block per relation. Buckets built by scanning label arrays,
// weights staged transposed+bf16 in LDS, grouped GEMM via 16x16x32 MFMA.
//   A[m=lane&15][k=(lane>>4)*8+j]  (m120-verified)
//   B[k=(lane>>4)*8+j][n=lane&15]  -> read Wt[a=n][e=k] contiguously
//   C: col=lane&15, row=(lane>>4)*4+reg  (m89-verified)
// ---------------------------------------------------------------------------
__global__ __launch_bounds__(256) void proj_kernel(
    const float* __restrict__ curr_all, const float* __restrict__ msg,
    const int* __restrict__ msg_type, const int* __restrict__ r_label_node,
    const int* __restrict__ r_label_msg,
    const float* __restrict__ Q, const float* __restrict__ K,
    const float* __restrict__ V,
    float* __restrict__ q_all, float* __restrict__ k_all,
    float* __restrict__ v_all)
{
    const int r    = blockIdx.x;
    const int tid  = threadIdx.x;
    const int lane = tid & 63;
    const int wave = tid >> 6;
    const int col  = lane & 15;      // MFMA n / C-col
    const int quad = lane >> 4;      // MFMA k-group / C-row-group

    __shared__ unsigned short wq_s[EE * WSTR];   // Wt layouts: [a][e]
    __shared__ unsigned short wv_s[EE * WSTR];
    __shared__ unsigned short wk_s[EE * WSTR];
    __shared__ unsigned short x_s[32 * WSTR];    // 32-token bf16 A tile
    __shared__ int list_q[LCAP], list_k[LCAP];
    __shared__ int nq_s, nk_s;

    if (tid == 0) { nq_s = 0; nk_s = 0; }
    __syncthreads();

    // ---- build buckets ----
    for (int i = tid; i < NN; i += 256)
        if (r_label_node[i] == r) {
            int p = atomicAdd(&nq_s, 1);
            if (p < LCAP) list_q[p] = i * TT;            // token (n,0)
        }
    for (int j = tid; j < NN * MM; j += 256) {
        int rl = r_label_msg[j];
        int mt = msg_type[j];
        if (rl == r) {
            int n = j / MM, m = j - n * MM;
            int p = atomicAdd(&nq_s, 1);
            if (p < LCAP) list_q[p] = n * TT + m + 1;
        }
        if (mt == r) {
            int n = j / MM, m = j - n * MM;
            int p = atomicAdd(&nk_s, 1);
            if (p < LCAP) list_k[p] = n * TT + m + 1;
        }
    }

    // ---- stage Wt (transposed, bf16): thread t -> a = t&63, e-group t>>6 ----
    {
        const int a = tid & 63, g = tid >> 6;
        const float* Qp = Q + (size_t)r * EE * EE;
        const float* Kp = K + (size_t)r * EE * EE;
        const float* Vp = V + (size_t)r * EE * EE;
        unsigned short bq[16], bk[16], bv[16];
#pragma unroll
        for (int j = 0; j < 16; ++j) {
            int e = g * 16 + j;
            bq[j] = f2bf(Qp[e * EE + a]);      // coalesced across lanes (a)
            bk[j] = f2bf(Kp[e * EE + a]);
            bv[j] = f2bf(Vp[e * EE + a]);
        }
        unsigned short* dq = &wq_s[a * WSTR + g * 16];
        unsigned short* dk = &wk_s[a * WSTR + g * 16];
        unsigned short* dv = &wv_s[a * WSTR + g * 16];
        *(short8*)dq = *(short8*)&bq[0]; *(short8*)(dq + 8) = *(short8*)&bq[8];
        *(short8*)dk = *(short8*)&bk[0]; *(short8*)(dk + 8) = *(short8*)&bk[8];
        *(short8*)dv = *(short8*)&bv[0]; *(short8*)(dv + 8) = *(short8*)&bv[8];
    }
    __syncthreads();

    const int nq = min(nq_s, LCAP);
    const int nk = min(nk_s, LCAP);

    // ================= PHASE A: q and v over list_q, 32-token rounds =======
    // wave: mtile = wave&1 (16-token sub-tile), mat = wave>>1 (0=Q, 1=V)
    {
        const int mtile = wave & 1;
        const unsigned short* w_s = (wave >> 1) ? wv_s : wq_s;
        float* out = (wave >> 1) ? v_all : q_all;
        const int m = mtile * 16 + col;                 // A row for frags

        for (int base = 0; base < nq; base += 32) {
            {   // stage x: thread -> row tid>>3 (0..31), 8 floats at (tid&7)*8
                int row = tid >> 3;
                int idx = base + row;
                if (idx < nq) {
                    int token = list_q[idx];
                    int n = token >> 5, t = token & 31;
                    const float* src = (t == 0)
                        ? (curr_all + n * EE)
                        : (msg + ((size_t)n * MM + (t - 1)) * EE);
                    const float4 f0 = ((const float4*)src)[(tid & 7) * 2];
                    const float4 f1 = ((const float4*)src)[(tid & 7) * 2 + 1];
                    unsigned short b[8] = { f2bf(f0.x), f2bf(f0.y), f2bf(f0.z), f2bf(f0.w),
                                            f2bf(f1.x), f2bf(f1.y), f2bf(f1.z), f2bf(f1.w) };
                    *(short8*)&x_s[row * WSTR + (tid & 7) * 8] = *(short8*)b;
                }
            }
            __syncthreads();

            f32x4 acc[4] = {{0,0,0,0},{0,0,0,0},{0,0,0,0},{0,0,0,0}};
#pragma unroll
            for (int kk = 0; kk < 2; ++kk) {
                short8 af = *(const short8*)&x_s[m * WSTR + kk * 32 + quad * 8];
#pragma unroll
                for (int nt = 0; nt < 4; ++nt) {
                    short8 bf = *(const short8*)&w_s[(nt * 16 + col) * WSTR + kk * 32 + quad * 8];
                    acc[nt] = __builtin_amdgcn_mfma_f32_16x16x32_bf16(af, bf, acc[nt], 0, 0, 0);
                }
            }
#pragma unroll
            for (int nt = 0; nt < 4; ++nt)
#pragma unroll
                for (int reg = 0; reg < 4; ++reg) {
                    int rrow = mtile * 16 + quad * 4 + reg;
                    int idx = base + rrow;
                    if (idx < nq) {
                        int token = list_q[idx];
                        out[(size_t)token * EE + nt * 16 + col] = acc[nt][reg];
                    }
                }
            __syncthreads();
        }
    }

    // ================= PHASE B: k over list_k ==============================
    // wave: mtile = wave&1, n-half = wave>>1 (n-tiles {2h, 2h+1})
    {
        const int mtile = wave & 1;
        const int nh = wave >> 1;
        const int m = mtile * 16 + col;

        for (int base = 0; base < nk; base += 32) {
            {
                int row = tid >> 3;
                int idx = base + row;
                if (idx < nk) {
                    int token = list_k[idx];
                    int n = token >> 5, t = token & 31;   // t >= 1 always
                    const float* src = msg + ((size_t)n * MM + (t - 1)) * EE;
                    const float4 f0 = ((const float4*)src)[(tid & 7) * 2];
                    const float4 f1 = ((const float4*)src)[(tid & 7) * 2 + 1];
                    unsigned short b[8] = { f2bf(f0.x), f2bf(f0.y), f2bf(f0.z), f2bf(f0.w),
                                            f2bf(f1.x), f2bf(f1.y), f2bf(f1.z), f2bf(f1.w) };
                    *(short8*)&x_s[row * WSTR + (tid & 7) * 8] = *(short8*)b;
                }
            }
            __syncthreads();

            f32x4 acc[2] = {{0,0,0,0},{0,0,0,0}};
#pragma unroll
            for (int kk = 0; kk < 2; ++kk) {
                short8 af = *(const short8*)&x_s[m * WSTR + kk * 32 + quad * 8];
#pragma unroll
                for (int j = 0; j < 2; ++j) {
                    int nt = nh * 2 + j;
                    short8 bf = *(const short8*)&wk_s[(nt * 16 + col) * WSTR + kk * 32 + quad * 8];
                    acc[j] = __builtin_amdgcn_mfma_f32_16x16x32_bf16(af, bf, acc[j], 0, 0, 0);
                }
            }
#pragma unroll
            for (int j = 0; j < 2; ++j)
#pragma unroll
                for (int reg = 0; reg < 4; ++reg) {
                    int rrow = mtile * 16 + quad * 4 + reg;
                    int idx = base + rrow;
                    if (idx < nk) {
                        int token = list_k[idx];
                        k_all[(size_t)token * EE + (nh * 2 + j) * 16 + col] = acc[j][reg];
                    }
                }
            __syncthreads();
        }
    }
}

// ---------------------------------------------------------------------------
// attn: one block per node; q/k/v contiguous [32][64] f32 rows.
// ---------------------------------------------------------------------------
__global__ __launch_bounds__(256) void attn_kernel(
    const float* __restrict__ q_all, const float* __restrict__ k_all,
    const float* __restrict__ v_all, const float* __restrict__ ffn_w,
    const float* __restrict__ ffn_b, float* __restrict__ out)
{
    const int n = blockIdx.x, tid = threadIdx.x;
    __shared__ float q_s[TT][68], k_s[TT][68], v_s[TT][68];
    __shared__ float s_s[TT][TT + 1];
    __shared__ float att0[TT];
    __shared__ float pooled[EE];

    {
        const float4* qg = (const float4*)(q_all + (size_t)n * TT * EE);
        const float4* kg = (const float4*)(k_all + (size_t)n * TT * EE);
        const float4* vg = (const float4*)(v_all + (size_t)n * TT * EE);
        for (int i = tid; i < TT * EE / 4; i += 256) {
            int row = i >> 4, c = i & 15;
            ((float4*)&q_s[row][0])[c] = qg[i];
            ((float4*)&k_s[row][0])[c] = kg[i];
            ((float4*)&v_s[row][0])[c] = vg[i];
        }
    }
    __syncthreads();

    {   // scores s[qi][ki] = dot(q[qi],k[ki]) / 8
        const int ki = tid & 31;
        for (int qi = tid >> 5; qi < TT; qi += 8) {
            const float4* qp = (const float4*)&q_s[qi][0];
            const float4* kp = (const float4*)&k_s[ki][0];
            float acc = 0.f;
            for (int e4 = 0; e4 < EE / 4; ++e4) {
                float4 a = qp[e4], b = kp[e4];
                acc += a.x * b.x + a.y * b.y + a.z * b.z + a.w * b.w;
            }
            s_s[qi][ki] = acc * 0.125f;
        }
    }
    __syncthreads();

    // softmax over the QUERY axis per column; only row 0 of att needed
    if (tid < TT) {
        float mx = -INFINITY;
        for (int qi = 0; qi < TT; ++qi) mx = fmaxf(mx, s_s[qi][tid]);
        float sum = 0.f;
        for (int qi = 0; qi < TT; ++qi) sum += __expf(s_s[qi][tid] - mx);
        att0[tid] = __expf(s_s[0][tid] - mx) / sum;
    }
    __syncthreads();

    if (tid < EE) {
        float acc = 0.f;
        for (int ki = 0; ki < TT; ++ki)
            acc = fmaf(att0[ki], v_s[ki][tid], acc);
        pooled[tid] = acc;
    }
    __syncthreads();

    if (tid < EE) {
        float acc = ffn_b[tid];
        for (int a = 0; a < EE; ++a)
            acc = fmaf(pooled[a], ffn_w[a * EE + tid], acc);
        out[n * EE + tid] = acc;
    }
}

extern "C" void kernel_launch(void* const* d_in, const int* in_sizes, int n_in,
                              void* d_out, int out_size, void* d_ws, size_t ws_size,
                              hipStream_t stream) {
    const float* h            = (const float*)d_in[0];
    const float* msg          = (const float*)d_in[1];
    const int*   msg_type     = (const int*)  d_in[2];
    const int*   r_label_node = (const int*)  d_in[3];
    const int*   r_label_msg  = (const int*)  d_in[4];
    const float* W_self       = (const float*)d_in[5];
    const float* Q            = (const float*)d_in[6];
    const float* K            = (const float*)d_in[7];
    const float* V            = (const float*)d_in[8];
    const float* ffn_w        = (const float*)d_in[9];
    const float* ffn_b        = (const float*)d_in[10];
    float*       out          = (float*)d_out;

    // workspace: curr_all [512*64] | q_all | k_all | v_all (each 512*32*64 f32)
    float* curr_all = (float*)d_ws;
    float* q_all = curr_all + NN * EE;
    float* k_all = q_all + (size_t)NN * TT * EE;
    float* v_all = k_all + (size_t)NN * TT * EE;

    prep_kernel<<<NN, 64, 0, stream>>>(h, W_self, K, curr_all, k_all);
    proj_kernel<<<NREL, 256, 0, stream>>>(curr_all, msg, msg_type, r_label_node,
                                          r_label_msg, Q, K, V,
                                          q_all, k_all, v_all);
    attn_kernel<<<NN, 256, 0, stream>>>(q_all, k_all, v_all, ffn_w, ffn_b, out);
}

// Round 4
// 123.685 us; speedup vs baseline: 1.0897x; 1.0338x over previous
//
#include <hip/hip_runtime.h>
#include <math.h>

#define NN 512
#define MM 31
#define TT 32            // M+1 tokens per node
#define EE 64            // INP = EMB = ATT
#define NREL 200
#define SELF_LOOP 200
#define QCAP 192         // per-relation list capacity (mean 82, sigma ~9)
#define NT 6             // 32-token tiles per relation: covers QCAP
#define WSTR 72          // bf16 LDS row stride (16B-aligned, 2-way banks max)

typedef short  short8 __attribute__((ext_vector_type(8)));
typedef float  f32x4  __attribute__((ext_vector_type(4)));

__device__ __forceinline__ unsigned short f2bf(float f) {
    union { float f; unsigned int u; } a; a.f = f;
    unsigned int r = a.u + 0x7FFFu + ((a.u >> 16) & 1u);   // RNE
    return (unsigned short)(r >> 16);
}

// ---------------------------------------------------------------------------
// prep+scan: per node — classify this node's 32 labels into global relation
// buckets (atomics), compute curr = h @ W_self, and k[n][0] = curr @ K[200]
// (token 0's kx index is ALWAYS the self-loop relation 200).
// ---------------------------------------------------------------------------
__global__ __launch_bounds__(64) void prep_scan_kernel(
    const float* __restrict__ h, const float* __restrict__ W_self,
    const float* __restrict__ K,
    const int* __restrict__ msg_type, const int* __restrict__ r_label_node,
    const int* __restrict__ r_label_msg,
    int* __restrict__ cnt_q, int* __restrict__ cnt_k,
    int* __restrict__ list_q, int* __restrict__ list_k,
    float* __restrict__ curr_all, float* __restrict__ k_all)
{
    const int n = blockIdx.x, a = threadIdx.x;

    // ---- scatter this node's tokens into relation buckets ----
    if (a == 0) {
        int r = r_label_node[n];
        int p = atomicAdd(&cnt_q[r], 1);
        if (p < QCAP) list_q[r * QCAP + p] = n * TT;        // token (n,0)
    }
    if (a < MM) {
        int j  = n * MM + a;
        int rl = r_label_msg[j];
        int p  = atomicAdd(&cnt_q[rl], 1);
        if (p < QCAP) list_q[rl * QCAP + p] = n * TT + a + 1;
        int mt = msg_type[j];
        int p2 = atomicAdd(&cnt_k[mt], 1);
        if (p2 < QCAP) list_k[mt * QCAP + p2] = n * TT + a + 1;
    }

    // ---- curr = h[n] @ W_self ----
    __shared__ float c_s[EE];
    const float* hrow = h + n * EE;
    float acc = 0.f;
#pragma unroll 8
    for (int e = 0; e < EE; ++e)
        acc = fmaf(hrow[e], W_self[e * EE + a], acc);
    curr_all[n * EE + a] = acc;
    c_s[a] = acc;
    __syncthreads();

    // ---- k[n][0] = curr @ K[SELF_LOOP] ----
    const float* K200 = K + (size_t)SELF_LOOP * EE * EE;
    float k0 = 0.f;
#pragma unroll 8
    for (int e = 0; e < EE; ++e)
        k0 = fmaf(c_s[e], K200[e * EE + a], k0);
    k_all[(size_t)n * TT * EE + a] = k0;
}

// ---------------------------------------------------------------------------
// proj_tile: block = (relation r, tile t). Handles 32 q-tokens AND 32
// k-tokens of r via 16x16x32 bf16 MFMA. Weights staged transposed bf16.
//   A[m=lane&15][k=(lane>>4)*8+j], B[k][n=lane&15] from Wt[a=n][e=k],
//   C: col=lane&15, row=(lane>>4)*4+reg  (verified round 3)
// ---------------------------------------------------------------------------
__global__ __launch_bounds__(256) void proj_tile_kernel(
    const float* __restrict__ curr_all, const float* __restrict__ msg,
    const float* __restrict__ Q, const float* __restrict__ K,
    const float* __restrict__ V,
    const int* __restrict__ cnt_q, const int* __restrict__ cnt_k,
    const int* __restrict__ list_q, const int* __restrict__ list_k,
    float* __restrict__ q_all, float* __restrict__ k_all,
    float* __restrict__ v_all)
{
    const int r    = blockIdx.x / NT;
    const int tile = blockIdx.x % NT;
    const int tid  = threadIdx.x;
    const int lane = tid & 63;
    const int wave = tid >> 6;
    const int col  = lane & 15;
    const int quad = lane >> 4;

    const int nq = min(cnt_q[r], QCAP);
    const int nk = min(cnt_k[r], QCAP);
    const int q0 = tile * 32, k0 = tile * 32;
    const bool do_q = q0 < nq;
    const bool do_k = k0 < nk;
    if (!do_q && !do_k) return;                  // block-uniform early exit

    __shared__ unsigned short wq_s[EE * WSTR];   // Wt: [a][e] bf16
    __shared__ unsigned short wk_s[EE * WSTR];
    __shared__ unsigned short wv_s[EE * WSTR];
    __shared__ unsigned short x_s[64 * WSTR];    // rows 0..31 q-side, 32..63 k-side
    __shared__ int tq_s[32], tk_s[32];           // this tile's token ids

    // ---- stage weights (transposed bf16): thread -> a = tid&63, e-grp tid>>6
    {
        const int a = tid & 63, g = tid >> 6;
        if (do_q) {
            const float* Qp = Q + (size_t)r * EE * EE;
            const float* Vp = V + (size_t)r * EE * EE;
            unsigned short bq[16], bv[16];
#pragma unroll
            for (int j = 0; j < 16; ++j) {
                int e = g * 16 + j;
                bq[j] = f2bf(Qp[e * EE + a]);
                bv[j] = f2bf(Vp[e * EE + a]);
            }
            unsigned short* dq = &wq_s[a * WSTR + g * 16];
            unsigned short* dv = &wv_s[a * WSTR + g * 16];
            *(short8*)dq = *(short8*)&bq[0]; *(short8*)(dq + 8) = *(short8*)&bq[8];
            *(short8*)dv = *(short8*)&bv[0]; *(short8*)(dv + 8) = *(short8*)&bv[8];
        }
        if (do_k) {
            const float* Kp = K + (size_t)r * EE * EE;
            unsigned short bk[16];
#pragma unroll
            for (int j = 0; j < 16; ++j) {
                int e = g * 16 + j;
                bk[j] = f2bf(Kp[e * EE + a]);
            }
            unsigned short* dk = &wk_s[a * WSTR + g * 16];
            *(short8*)dk = *(short8*)&bk[0]; *(short8*)(dk + 8) = *(short8*)&bk[8];
        }
    }

    // ---- stage token ids for this tile ----
    if (tid < 32) {
        tq_s[tid] = (do_q && q0 + tid < nq) ? list_q[r * QCAP + q0 + tid] : -1;
    } else if (tid < 64) {
        int i = tid - 32;
        tk_s[i] = (do_k && k0 + i < nk) ? list_k[r * QCAP + k0 + i] : -1;
    }

    // ---- stage x rows (4 threads/row, 16 floats each -> bf16) ----
    {
        const int row = tid >> 2;                // 0..63
        const int fo  = (tid & 3) * 4;           // float4 start col
        const bool qside = row < 32;
        const int li = qside ? (q0 + row) : (k0 + row - 32);
        const bool valid = qside ? (do_q && li < nq) : (do_k && li < nk);
        if (valid) {
            int token = qside ? list_q[r * QCAP + li] : list_k[r * QCAP + li];
            int n = token >> 5, t = token & 31;
            const float* src = (t == 0)
                ? (curr_all + n * EE)
                : (msg + ((size_t)n * MM + (t - 1)) * EE);
            float4 f0 = ((const float4*)src)[fo + 0];
            float4 f1 = ((const float4*)src)[fo + 1];
            float4 f2 = ((const float4*)src)[fo + 2];
            float4 f3 = ((const float4*)src)[fo + 3];
            unsigned short b[16] = {
                f2bf(f0.x), f2bf(f0.y), f2bf(f0.z), f2bf(f0.w),
                f2bf(f1.x), f2bf(f1.y), f2bf(f1.z), f2bf(f1.w),
                f2bf(f2.x), f2bf(f2.y), f2bf(f2.z), f2bf(f2.w),
                f2bf(f3.x), f2bf(f3.y), f2bf(f3.z), f2bf(f3.w) };
            unsigned short* d = &x_s[row * WSTR + fo * 4];
            *(short8*)d       = *(short8*)&b[0];
            *(short8*)(d + 8) = *(short8*)&b[8];
        }
    }
    __syncthreads();

    // ---- GEMM A: q and v (wave: mtile = w&1, mat = w>>1) ----
    if (do_q) {
        const int mtile = wave & 1;
        const unsigned short* w_s = (wave >> 1) ? wv_s : wq_s;
        float* outp = (wave >> 1) ? v_all : q_all;
        const int m = mtile * 16 + col;
        f32x4 acc[4] = {{0,0,0,0},{0,0,0,0},{0,0,0,0},{0,0,0,0}};
#pragma unroll
        for (int kk = 0; kk < 2; ++kk) {
            short8 af = *(const short8*)&x_s[m * WSTR + kk * 32 + quad * 8];
#pragma unroll
            for (int nt = 0; nt < 4; ++nt) {
                short8 bf = *(const short8*)&w_s[(nt * 16 + col) * WSTR + kk * 32 + quad * 8];
                acc[nt] = __builtin_amdgcn_mfma_f32_16x16x32_bf16(af, bf, acc[nt], 0, 0, 0);
            }
        }
#pragma unroll
        for (int nt = 0; nt < 4; ++nt)
#pragma unroll
            for (int reg = 0; reg < 4; ++reg) {
                int rrow = mtile * 16 + quad * 4 + reg;
                int token = tq_s[rrow];
                if (token >= 0)
                    outp[(size_t)token * EE + nt * 16 + col] = acc[nt][reg];
            }
    }

    // ---- GEMM B: k (wave: mtile = w&1, n-half = w>>1) ----
    if (do_k) {
        const int mtile = wave & 1;
        const int nh = wave >> 1;
        const int m = 32 + mtile * 16 + col;     // k-side x rows
        f32x4 acc[2] = {{0,0,0,0},{0,0,0,0}};
#pragma unroll
        for (int kk = 0; kk < 2; ++kk) {
            short8 af = *(const short8*)&x_s[m * WSTR + kk * 32 + quad * 8];
#pragma unroll
            for (int j = 0; j < 2; ++j) {
                int nt = nh * 2 + j;
                short8 bf = *(const short8*)&wk_s[(nt * 16 + col) * WSTR + kk * 32 + quad * 8];
                acc[j] = __builtin_amdgcn_mfma_f32_16x16x32_bf16(af, bf, acc[j], 0, 0, 0);
            }
        }
#pragma unroll
        for (int j = 0; j < 2; ++j)
#pragma unroll
            for (int reg = 0; reg < 4; ++reg) {
                int rrow = mtile * 16 + quad * 4 + reg;
                int token = tk_s[rrow];
                if (token >= 0)
                    k_all[(size_t)token * EE + (nh * 2 + j) * 16 + col] = acc[j][reg];
            }
    }
}

// ---------------------------------------------------------------------------
// attn: one block per node; q/k/v contiguous [32][64] f32 rows.
// ---------------------------------------------------------------------------
__global__ __launch_bounds__(256) void attn_kernel(
    const float* __restrict__ q_all, const float* __restrict__ k_all,
    const float* __restrict__ v_all, const float* __restrict__ ffn_w,
    const float* __restrict__ ffn_b, float* __restrict__ out)
{
    const int n = blockIdx.x, tid = threadIdx.x;
    __shared__ float q_s[TT][68], k_s[TT][68], v_s[TT][68];
    __shared__ float s_s[TT][TT + 1];
    __shared__ float att0[TT];
    __shared__ float pooled[EE];

    {
        const float4* qg = (const float4*)(q_all + (size_t)n * TT * EE);
        const float4* kg = (const float4*)(k_all + (size_t)n * TT * EE);
        const float4* vg = (const float4*)(v_all + (size_t)n * TT * EE);
        for (int i = tid; i < TT * EE / 4; i += 256) {
            int row = i >> 4, c = i & 15;
            ((float4*)&q_s[row][0])[c] = qg[i];
            ((float4*)&k_s[row][0])[c] = kg[i];
            ((float4*)&v_s[row][0])[c] = vg[i];
        }
    }
    __syncthreads();

    {   // scores s[qi][ki] = dot(q[qi],k[ki]) / 8
        const int ki = tid & 31;
        for (int qi = tid >> 5; qi < TT; qi += 8) {
            const float4* qp = (const float4*)&q_s[qi][0];
            const float4* kp = (const float4*)&k_s[ki][0];
            float acc = 0.f;
            for (int e4 = 0; e4 < EE / 4; ++e4) {
                float4 a = qp[e4], b = kp[e4];
                acc += a.x * b.x + a.y * b.y + a.z * b.z + a.w * b.w;
            }
            s_s[qi][ki] = acc * 0.125f;
        }
    }
    __syncthreads();

    // softmax over the QUERY axis per column; only row 0 of att needed
    if (tid < TT) {
        float mx = -INFINITY;
        for (int qi = 0; qi < TT; ++qi) mx = fmaxf(mx, s_s[qi][tid]);
        float sum = 0.f;
        for (int qi = 0; qi < TT; ++qi) sum += __expf(s_s[qi][tid] - mx);
        att0[tid] = __expf(s_s[0][tid] - mx) / sum;
    }
    __syncthreads();

    if (tid < EE) {
        float acc = 0.f;
        for (int ki = 0; ki < TT; ++ki)
            acc = fmaf(att0[ki], v_s[ki][tid], acc);
        pooled[tid] = acc;
    }
    __syncthreads();

    if (tid < EE) {
        float acc = ffn_b[tid];
        for (int a = 0; a < EE; ++a)
            acc = fmaf(pooled[a], ffn_w[a * EE + tid], acc);
        out[n * EE + tid] = acc;
    }
}

extern "C" void kernel_launch(void* const* d_in, const int* in_sizes, int n_in,
                              void* d_out, int out_size, void* d_ws, size_t ws_size,
                              hipStream_t stream) {
    const float* h            = (const float*)d_in[0];
    const float* msg          = (const float*)d_in[1];
    const int*   msg_type     = (const int*)  d_in[2];
    const int*   r_label_node = (const int*)  d_in[3];
    const int*   r_label_msg  = (const int*)  d_in[4];
    const float* W_self       = (const float*)d_in[5];
    const float* Q            = (const float*)d_in[6];
    const float* K            = (const float*)d_in[7];
    const float* V            = (const float*)d_in[8];
    const float* ffn_w        = (const float*)d_in[9];
    const float* ffn_b        = (const float*)d_in[10];
    float*       out          = (float*)d_out;

    // ws layout: cnt_q[200]|cnt_k[200]|pad -> 512 ints, then lists, then f32
    int* cnt_q  = (int*)d_ws;
    int* cnt_k  = cnt_q + NREL;
    int* list_q = (int*)d_ws + 512;
    int* list_k = list_q + NREL * QCAP;
    float* curr_all = (float*)(list_k + NREL * QCAP);
    float* q_all = curr_all + NN * EE;
    float* k_all = q_all + (size_t)NN * TT * EE;
    float* v_all = k_all + (size_t)NN * TT * EE;

    hipMemsetAsync(cnt_q, 0, 2 * NREL * sizeof(int), stream);
    prep_scan_kernel<<<NN, 64, 0, stream>>>(h, W_self, K, msg_type,
                                            r_label_node, r_label_msg,
                                            cnt_q, cnt_k, list_q, list_k,
                                            curr_all, k_all);
    proj_tile_kernel<<<NREL * NT, 256, 0, stream>>>(curr_all, msg, Q, K, V,
                                                    cnt_q, cnt_k, list_q, list_k,
                                                    q_all, k_all, v_all);
    attn_kernel<<<NN, 256, 0, stream>>>(q_all, k_all, v_all, ffn_w, ffn_b, out);
}

// Round 6
// 109.378 us; speedup vs baseline: 1.2322x; 1.1308x over previous
//
#include <hip/hip_runtime.h>
#include <math.h>

#define NN 512
#define MM 31
#define TT 32            // M+1 tokens per node
#define EE 64            // INP = EMB = ATT
#define NREL 200
#define SELF_LOOP 200
#define QCAP 192         // per-relation list capacity (mean ~82, ~12 sigma)
#define NT 6             // 32-token tiles per relation: covers QCAP
#define WSTR 72          // bf16 LDS row stride (16B-aligned, 2-way banks max)
#define CPAD 32          // one counter per 128B cache line (kills same-line atomic serialization)

typedef short  short8 __attribute__((ext_vector_type(8)));
typedef float  f32x4  __attribute__((ext_vector_type(4)));

__device__ __forceinline__ unsigned short f2bf(float f) {
    union { float f; unsigned int u; } a; a.f = f;
    unsigned int r = a.u + 0x7FFFu + ((a.u >> 16) & 1u);   // RNE
    return (unsigned short)(r >> 16);
}

// ---------------------------------------------------------------------------
// prep+scan: per node — classify this node's 32 labels into global relation
// buckets (padded counters), compute curr = h @ W_self, and k[n][0] =
// curr @ K[200] (token 0's kx index is ALWAYS the self-loop relation 200).
// ---------------------------------------------------------------------------
__global__ __launch_bounds__(64) void prep_scan_kernel(
    const float* __restrict__ h, const float* __restrict__ W_self,
    const float* __restrict__ K,
    const int* __restrict__ msg_type, const int* __restrict__ r_label_node,
    const int* __restrict__ r_label_msg,
    int* __restrict__ cnt_q, int* __restrict__ cnt_k,
    int* __restrict__ list_q, int* __restrict__ list_k,
    float* __restrict__ curr_all, float* __restrict__ k_all)
{
    const int n = blockIdx.x, a = threadIdx.x;

    // ---- scatter this node's tokens into relation buckets ----
    if (a == 0) {
        int r = r_label_node[n];
        int p = atomicAdd(&cnt_q[r * CPAD], 1);
        if (p < QCAP) list_q[r * QCAP + p] = n * TT;        // token (n,0)
    }
    if (a < MM) {
        int j  = n * MM + a;
        int rl = r_label_msg[j];
        int p  = atomicAdd(&cnt_q[rl * CPAD], 1);
        if (p < QCAP) list_q[rl * QCAP + p] = n * TT + a + 1;
        int mt = msg_type[j];
        int p2 = atomicAdd(&cnt_k[mt * CPAD], 1);
        if (p2 < QCAP) list_k[mt * QCAP + p2] = n * TT + a + 1;
    }

    // ---- curr = h[n] @ W_self ----
    __shared__ float c_s[EE];
    const float* hrow = h + n * EE;
    float acc = 0.f;
#pragma unroll 8
    for (int e = 0; e < EE; ++e)
        acc = fmaf(hrow[e], W_self[e * EE + a], acc);
    curr_all[n * EE + a] = acc;
    c_s[a] = acc;
    __syncthreads();

    // ---- k[n][0] = curr @ K[SELF_LOOP] ----
    const float* K200 = K + (size_t)SELF_LOOP * EE * EE;
    float k0 = 0.f;
#pragma unroll 8
    for (int e = 0; e < EE; ++e)
        k0 = fmaf(c_s[e], K200[e * EE + a], k0);
    k_all[(size_t)n * TT * EE + a] = k0;
}

// ---------------------------------------------------------------------------
// proj_tile: block = (relation r, tile t). Handles 32 q-tokens AND 32
// k-tokens of r via 16x16x32 bf16 MFMA. Weights staged transposed bf16.
//   A[m=lane&15][k=(lane>>4)*8+j], B[k][n=lane&15] from Wt[a=n][e=k],
//   C: col=lane&15, row=(lane>>4)*4+reg  (verified rounds 3-4)
// ---------------------------------------------------------------------------
__global__ __launch_bounds__(256) void proj_tile_kernel(
    const float* __restrict__ curr_all, const float* __restrict__ msg,
    const float* __restrict__ Q, const float* __restrict__ K,
    const float* __restrict__ V,
    const int* __restrict__ cnt_q, const int* __restrict__ cnt_k,
    const int* __restrict__ list_q, const int* __restrict__ list_k,
    float* __restrict__ q_all, float* __restrict__ k_all,
    float* __restrict__ v_all)
{
    const int r    = blockIdx.x / NT;
    const int tile = blockIdx.x % NT;
    const int tid  = threadIdx.x;
    const int lane = tid & 63;
    const int wave = tid >> 6;
    const int col  = lane & 15;
    const int quad = lane >> 4;

    const int nq = min(cnt_q[r * CPAD], QCAP);
    const int nk = min(cnt_k[r * CPAD], QCAP);
    const int q0 = tile * 32;
    const bool do_q = q0 < nq;
    const bool do_k = q0 < nk;
    if (!do_q && !do_k) return;                  // block-uniform early exit

    __shared__ unsigned short wq_s[EE * WSTR];   // Wt: [a][e] bf16
    __shared__ unsigned short wk_s[EE * WSTR];
    __shared__ unsigned short wv_s[EE * WSTR];
    __shared__ unsigned short x_s[64 * WSTR];    // rows 0..31 q-side, 32..63 k-side
    __shared__ int tq_s[32], tk_s[32];           // this tile's token ids

    // ---- stage weights (transposed bf16): thread -> a = tid&63, e-grp tid>>6
    {
        const int a = tid & 63, g = tid >> 6;
        if (do_q) {
            const float* Qp = Q + (size_t)r * EE * EE;
            const float* Vp = V + (size_t)r * EE * EE;
            unsigned short bq[16], bv[16];
#pragma unroll
            for (int j = 0; j < 16; ++j) {
                int e = g * 16 + j;
                bq[j] = f2bf(Qp[e * EE + a]);
                bv[j] = f2bf(Vp[e * EE + a]);
            }
            unsigned short* dq = &wq_s[a * WSTR + g * 16];
            unsigned short* dv = &wv_s[a * WSTR + g * 16];
            *(short8*)dq = *(short8*)&bq[0]; *(short8*)(dq + 8) = *(short8*)&bq[8];
            *(short8*)dv = *(short8*)&bv[0]; *(short8*)(dv + 8) = *(short8*)&bv[8];
        }
        if (do_k) {
            const float* Kp = K + (size_t)r * EE * EE;
            unsigned short bk[16];
#pragma unroll
            for (int j = 0; j < 16; ++j) {
                int e = g * 16 + j;
                bk[j] = f2bf(Kp[e * EE + a]);
            }
            unsigned short* dk = &wk_s[a * WSTR + g * 16];
            *(short8*)dk = *(short8*)&bk[0]; *(short8*)(dk + 8) = *(short8*)&bk[8];
        }
    }

    // ---- stage token ids for this tile ----
    if (tid < 32) {
        tq_s[tid] = (do_q && q0 + tid < nq) ? list_q[r * QCAP + q0 + tid] : -1;
    } else if (tid < 64) {
        int i = tid - 32;
        tk_s[i] = (do_k && q0 + i < nk) ? list_k[r * QCAP + q0 + i] : -1;
    }

    // ---- stage x rows (4 threads/row, 16 floats each -> bf16) ----
    {
        const int row = tid >> 2;                // 0..63
        const int fo  = (tid & 3) * 4;           // float4 start index
        const bool qside = row < 32;
        const int li = qside ? (q0 + row) : (q0 + row - 32);
        const bool valid = qside ? (do_q && li < nq) : (do_k && li < nk);
        if (valid) {
            int token = qside ? list_q[r * QCAP + li] : list_k[r * QCAP + li];
            int n = token >> 5, t = token & 31;
            const float* src = (t == 0)
                ? (curr_all + n * EE)
                : (msg + ((size_t)n * MM + (t - 1)) * EE);
            float4 f0 = ((const float4*)src)[fo + 0];
            float4 f1 = ((const float4*)src)[fo + 1];
            float4 f2 = ((const float4*)src)[fo + 2];
            float4 f3 = ((const float4*)src)[fo + 3];
            unsigned short b[16] = {
                f2bf(f0.x), f2bf(f0.y), f2bf(f0.z), f2bf(f0.w),
                f2bf(f1.x), f2bf(f1.y), f2bf(f1.z), f2bf(f1.w),
                f2bf(f2.x), f2bf(f2.y), f2bf(f2.z), f2bf(f2.w),
                f2bf(f3.x), f2bf(f3.y), f2bf(f3.z), f2bf(f3.w) };
            unsigned short* d = &x_s[row * WSTR + fo * 4];
            *(short8*)d       = *(short8*)&b[0];
            *(short8*)(d + 8) = *(short8*)&b[8];
        }
    }
    __syncthreads();

    // ---- GEMM A: q and v (wave: mtile = w&1, mat = w>>1) ----
    if (do_q) {
        const int mtile = wave & 1;
        const unsigned short* w_s = (wave >> 1) ? wv_s : wq_s;
        float* outp = (wave >> 1) ? v_all : q_all;
        const int m = mtile * 16 + col;
        f32x4 acc[4] = {{0,0,0,0},{0,0,0,0},{0,0,0,0},{0,0,0,0}};
#pragma unroll
        for (int kk = 0; kk < 2; ++kk) {
            short8 af = *(const short8*)&x_s[m * WSTR + kk * 32 + quad * 8];
#pragma unroll
            for (int nt = 0; nt < 4; ++nt) {
                short8 bf = *(const short8*)&w_s[(nt * 16 + col) * WSTR + kk * 32 + quad * 8];
                acc[nt] = __builtin_amdgcn_mfma_f32_16x16x32_bf16(af, bf, acc[nt], 0, 0, 0);
            }
        }
#pragma unroll
        for (int nt = 0; nt < 4; ++nt)
#pragma unroll
            for (int reg = 0; reg < 4; ++reg) {
                int rrow = mtile * 16 + quad * 4 + reg;
                int token = tq_s[rrow];
                if (token >= 0)
                    outp[(size_t)token * EE + nt * 16 + col] = acc[nt][reg];
            }
    }

    // ---- GEMM B: k (wave: mtile = w&1, n-half = w>>1) ----
    if (do_k) {
        const int mtile = wave & 1;
        const int nh = wave >> 1;
        const int m = 32 + mtile * 16 + col;     // k-side x rows
        f32x4 acc[2] = {{0,0,0,0},{0,0,0,0}};
#pragma unroll
        for (int kk = 0; kk < 2; ++kk) {
            short8 af = *(const short8*)&x_s[m * WSTR + kk * 32 + quad * 8];
#pragma unroll
            for (int j = 0; j < 2; ++j) {
                int nt = nh * 2 + j;
                short8 bf = *(const short8*)&wk_s[(nt * 16 + col) * WSTR + kk * 32 + quad * 8];
                acc[j] = __builtin_amdgcn_mfma_f32_16x16x32_bf16(af, bf, acc[j], 0, 0, 0);
            }
        }
#pragma unroll
        for (int j = 0; j < 2; ++j)
#pragma unroll
            for (int reg = 0; reg < 4; ++reg) {
                int rrow = mtile * 16 + quad * 4 + reg;
                int token = tk_s[rrow];
                if (token >= 0)
                    k_all[(size_t)token * EE + (nh * 2 + j) * 16 + col] = acc[j][reg];
            }
    }
}

// ---------------------------------------------------------------------------
// attn: one block per node; q/k/v contiguous [32][64] f32 rows.
// ---------------------------------------------------------------------------
__global__ __launch_bounds__(256) void attn_kernel(
    const float* __restrict__ q_all, const float* __restrict__ k_all,
    const float* __restrict__ v_all, const float* __restrict__ ffn_w,
    const float* __restrict__ ffn_b, float* __restrict__ out)
{
    const int n = blockIdx.x, tid = threadIdx.x;
    __shared__ float q_s[TT][68], k_s[TT][68], v_s[TT][68];
    __shared__ float s_s[TT][TT + 1];
    __shared__ float att0[TT];
    __shared__ float pooled[EE];

    {
        const float4* qg = (const float4*)(q_all + (size_t)n * TT * EE);
        const float4* kg = (const float4*)(k_all + (size_t)n * TT * EE);
        const float4* vg = (const float4*)(v_all + (size_t)n * TT * EE);
        for (int i = tid; i < TT * EE / 4; i += 256) {
            int row = i >> 4, c = i & 15;
            ((float4*)&q_s[row][0])[c] = qg[i];
            ((float4*)&k_s[row][0])[c] = kg[i];
            ((float4*)&v_s[row][0])[c] = vg[i];
        }
    }
    __syncthreads();

    {   // scores s[qi][ki] = dot(q[qi],k[ki]) / 8
        const int ki = tid & 31;
        for (int qi = tid >> 5; qi < TT; qi += 8) {
            const float4* qp = (const float4*)&q_s[qi][0];
            const float4* kp = (const float4*)&k_s[ki][0];
            float acc = 0.f;
            for (int e4 = 0; e4 < EE / 4; ++e4) {
                float4 a = qp[e4], b = kp[e4];
                acc += a.x * b.x + a.y * b.y + a.z * b.z + a.w * b.w;
            }
            s_s[qi][ki] = acc * 0.125f;
        }
    }
    __syncthreads();

    // softmax over the QUERY axis per column; only row 0 of att needed
    if (tid < TT) {
        float mx = -INFINITY;
        for (int qi = 0; qi < TT; ++qi) mx = fmaxf(mx, s_s[qi][tid]);
        float sum = 0.f;
        for (int qi = 0; qi < TT; ++qi) sum += __expf(s_s[qi][tid] - mx);
        att0[tid] = __expf(s_s[0][tid] - mx) / sum;
    }
    __syncthreads();

    if (tid < EE) {
        float acc = 0.f;
        for (int ki = 0; ki < TT; ++ki)
            acc = fmaf(att0[ki], v_s[ki][tid], acc);
        pooled[tid] = acc;
    }
    __syncthreads();

    if (tid < EE) {
        float acc = ffn_b[tid];
        for (int a = 0; a < EE; ++a)
            acc = fmaf(pooled[a], ffn_w[a * EE + tid], acc);
        out[n * EE + tid] = acc;
    }
}

extern "C" void kernel_launch(void* const* d_in, const int* in_sizes, int n_in,
                              void* d_out, int out_size, void* d_ws, size_t ws_size,
                              hipStream_t stream) {
    const float* h            = (const float*)d_in[0];
    const float* msg          = (const float*)d_in[1];
    const int*   msg_type     = (const int*)  d_in[2];
    const int*   r_label_node = (const int*)  d_in[3];
    const int*   r_label_msg  = (const int*)  d_in[4];
    const float* W_self       = (const float*)d_in[5];
    const float* Q            = (const float*)d_in[6];
    const float* K            = (const float*)d_in[7];
    const float* V            = (const float*)d_in[8];
    const float* ffn_w        = (const float*)d_in[9];
    const float* ffn_b        = (const float*)d_in[10];
    float*       out          = (float*)d_out;

    // ws layout: cnt_q[200*CPAD] | cnt_k[200*CPAD] | list_q | list_k | f32 bufs
    int* cnt_q  = (int*)d_ws;
    int* cnt_k  = cnt_q + NREL * CPAD;
    int* list_q = cnt_k + NREL * CPAD;
    int* list_k = list_q + NREL * QCAP;
    float* curr_all = (float*)(list_k + NREL * QCAP);
    float* q_all = curr_all + NN * EE;
    float* k_all = q_all + (size_t)NN * TT * EE;
    float* v_all = k_all + (size_t)NN * TT * EE;

    hipMemsetAsync(cnt_q, 0, 2 * NREL * CPAD * sizeof(int), stream);
    prep_scan_kernel<<<NN, 64, 0, stream>>>(h, W_self, K, msg_type,
                                            r_label_node, r_label_msg,
                                            cnt_q, cnt_k, list_q, list_k,
                                            curr_all, k_all);
    proj_tile_kernel<<<NREL * NT, 256, 0, stream>>>(curr_all, msg, Q, K, V,
                                                    cnt_q, cnt_k, list_q, list_k,
                                                    q_all, k_all, v_all);
    attn_kernel<<<NN, 256, 0, stream>>>(q_all, k_all, v_all, ffn_w, ffn_b, out);
}

// Round 7
// 108.713 us; speedup vs baseline: 1.2397x; 1.0061x over previous
//
#include <hip/hip_runtime.h>
#include <math.h>

#define NN 512
#define MM 31
#define TT 32            // M+1 tokens per node
#define EE 64            // INP = EMB = ATT
#define NREL 200
#define NMAT 201
#define SELF_LOOP 200
#define QCAP 192         // per-relation list capacity (mean ~82, ~12 sigma)
#define NT 6             // 32-token tiles per relation: covers QCAP
#define WSTR 72          // bf16 LDS row stride (16B-aligned, de-aliased banks)
#define CPAD 32          // one counter per 128B line (round-6 verified win)

typedef short  short8 __attribute__((ext_vector_type(8)));
typedef float  f32x4  __attribute__((ext_vector_type(4)));

__device__ __forceinline__ unsigned short f2bf(float f) {
    union { float f; unsigned int u; } a; a.f = f;
    unsigned int r = a.u + 0x7FFFu + ((a.u >> 16) & 1u);   // RNE
    return (unsigned short)(r >> 16);
}

// ---------------------------------------------------------------------------
// prep_convert: grid = 603 converter blocks + 512 node blocks.
//  bid < 603:  transpose+convert one [64,64] f32 matrix -> bf16 Wt[a][e]
//  bid >= 603: node n = bid-603: scan labels into buckets (padded counters),
//              curr = h@W_self, k[n][0] = curr@K[200] (f32, full precision).
// ---------------------------------------------------------------------------
__global__ __launch_bounds__(256) void prep_convert_kernel(
    const float* __restrict__ h, const float* __restrict__ W_self,
    const float* __restrict__ Q, const float* __restrict__ K,
    const float* __restrict__ V,
    const int* __restrict__ msg_type, const int* __restrict__ r_label_node,
    const int* __restrict__ r_label_msg,
    int* __restrict__ cnt_q, int* __restrict__ cnt_k,
    int* __restrict__ list_q, int* __restrict__ list_k,
    unsigned short* __restrict__ wt_q, unsigned short* __restrict__ wt_k,
    unsigned short* __restrict__ wt_v,
    float* __restrict__ curr_all, float* __restrict__ k_all)
{
    const int bid = blockIdx.x, tid = threadIdx.x;

    if (bid < 3 * NMAT) {
        // ================= converter block =================
        const int r   = bid % NMAT;
        const int mat = bid / NMAT;
        const float* src = (mat == 0 ? Q : mat == 1 ? K : V) + (size_t)r * EE * EE;
        unsigned short* dst = (mat == 0 ? wt_q : mat == 1 ? wt_k : wt_v)
                              + (size_t)r * EE * EE;
        __shared__ unsigned short t_s[EE * WSTR];    // [e][a], padded

        {   // load coalesced rows of src[e][a], convert, stage
            const int e = tid >> 2, aseg = (tid & 3) * 16;
            const float4* s4 = (const float4*)(src + e * EE + aseg);
            float4 f0 = s4[0], f1 = s4[1], f2 = s4[2], f3 = s4[3];
            unsigned short b[16] = {
                f2bf(f0.x), f2bf(f0.y), f2bf(f0.z), f2bf(f0.w),
                f2bf(f1.x), f2bf(f1.y), f2bf(f1.z), f2bf(f1.w),
                f2bf(f2.x), f2bf(f2.y), f2bf(f2.z), f2bf(f2.w),
                f2bf(f3.x), f2bf(f3.y), f2bf(f3.z), f2bf(f3.w) };
            unsigned short* d = &t_s[e * WSTR + aseg];
            *(short8*)d = *(short8*)&b[0];
            *(short8*)(d + 8) = *(short8*)&b[8];
        }
        __syncthreads();
        {   // emit transposed: row a, 16 e's per thread; lanes 0..3 cover row a
            const int a = tid >> 2, eseg = (tid & 3) * 16;
            unsigned short o[16];
#pragma unroll
            for (int j = 0; j < 16; ++j)
                o[j] = t_s[(eseg + j) * WSTR + a];
            unsigned short* d = dst + a * EE + eseg;
            *(short8*)d = *(short8*)&o[0];
            *(short8*)(d + 8) = *(short8*)&o[8];
        }
        return;
    }

    // ================= node block =================
    const int n = bid - 3 * NMAT;

    // ---- scatter labels into relation buckets ----
    if (tid < MM) {
        int j  = n * MM + tid;
        int rl = r_label_msg[j];
        int p  = atomicAdd(&cnt_q[rl * CPAD], 1);
        if (p < QCAP) list_q[rl * QCAP + p] = n * TT + tid + 1;
        int mt = msg_type[j];
        int p2 = atomicAdd(&cnt_k[mt * CPAD], 1);
        if (p2 < QCAP) list_k[mt * QCAP + p2] = n * TT + tid + 1;
    } else if (tid == 63) {
        int r = r_label_node[n];
        int p = atomicAdd(&cnt_q[r * CPAD], 1);
        if (p < QCAP) list_q[r * QCAP + p] = n * TT;
    }

    // ---- curr = h[n] @ W_self; k[n][0] = curr @ K[200] (threads 0..63) ----
    __shared__ float c_s[EE];
    if (tid < EE) {
        const float* hrow = h + n * EE;
        float acc = 0.f;
#pragma unroll 8
        for (int e = 0; e < EE; ++e)
            acc = fmaf(hrow[e], W_self[e * EE + tid], acc);
        curr_all[n * EE + tid] = acc;
        c_s[tid] = acc;
    }
    __syncthreads();
    if (tid < EE) {
        const float* K200 = K + (size_t)SELF_LOOP * EE * EE;
        float k0 = 0.f;
#pragma unroll 8
        for (int e = 0; e < EE; ++e)
            k0 = fmaf(c_s[e], K200[e * EE + tid], k0);
        k_all[(size_t)n * TT * EE + tid] = k0;
    }
}

// ---------------------------------------------------------------------------
// proj_tile: block = (relation r, tile t). 32 q-tokens AND 32 k-tokens via
// 16x16x32 bf16 MFMA. Weights now PRE-CONVERTED bf16 transposed — staging is
// a pure copy (2 short8 loads + 2 LDS stores per matrix per thread).
//   A[m=lane&15][k=(lane>>4)*8+j], B[k][n=lane&15] from Wt[a=n][e=k],
//   C: col=lane&15, row=(lane>>4)*4+reg  (verified rounds 3/4/6)
// ---------------------------------------------------------------------------
__global__ __launch_bounds__(256) void proj_tile_kernel(
    const float* __restrict__ curr_all, const float* __restrict__ msg,
    const unsigned short* __restrict__ wt_q,
    const unsigned short* __restrict__ wt_k,
    const unsigned short* __restrict__ wt_v,
    const int* __restrict__ cnt_q, const int* __restrict__ cnt_k,
    const int* __restrict__ list_q, const int* __restrict__ list_k,
    float* __restrict__ q_all, float* __restrict__ k_all,
    float* __restrict__ v_all)
{
    const int r    = blockIdx.x / NT;
    const int tile = blockIdx.x % NT;
    const int tid  = threadIdx.x;
    const int lane = tid & 63;
    const int wave = tid >> 6;
    const int col  = lane & 15;
    const int quad = lane >> 4;

    const int nq = min(cnt_q[r * CPAD], QCAP);
    const int nk = min(cnt_k[r * CPAD], QCAP);
    const int q0 = tile * 32;
    const bool do_q = q0 < nq;
    const bool do_k = q0 < nk;
    if (!do_q && !do_k) return;                  // block-uniform early exit

    __shared__ unsigned short wq_s[EE * WSTR];   // Wt: [a][e] bf16
    __shared__ unsigned short wk_s[EE * WSTR];
    __shared__ unsigned short wv_s[EE * WSTR];
    __shared__ unsigned short x_s[64 * WSTR];    // rows 0..31 q-side, 32..63 k-side
    __shared__ int tq_s[32], tk_s[32];

    // ---- stage weights: pure bf16 copy, coalesced ----
    {
        const int a = tid >> 2, seg = (tid & 3) * 16;
        const size_t go = (size_t)r * EE * EE + a * EE + seg;
        const int lo = a * WSTR + seg;
        if (do_q) {
            short8 w0 = *(const short8*)(wt_q + go);
            short8 w1 = *(const short8*)(wt_q + go + 8);
            *(short8*)&wq_s[lo] = w0; *(short8*)&wq_s[lo + 8] = w1;
            short8 v0 = *(const short8*)(wt_v + go);
            short8 v1 = *(const short8*)(wt_v + go + 8);
            *(short8*)&wv_s[lo] = v0; *(short8*)&wv_s[lo + 8] = v1;
        }
        if (do_k) {
            short8 k0_ = *(const short8*)(wt_k + go);
            short8 k1_ = *(const short8*)(wt_k + go + 8);
            *(short8*)&wk_s[lo] = k0_; *(short8*)&wk_s[lo + 8] = k1_;
        }
    }

    // ---- stage token ids ----
    if (tid < 32) {
        tq_s[tid] = (do_q && q0 + tid < nq) ? list_q[r * QCAP + q0 + tid] : -1;
    } else if (tid < 64) {
        int i = tid - 32;
        tk_s[i] = (do_k && q0 + i < nk) ? list_k[r * QCAP + q0 + i] : -1;
    }

    // ---- stage x rows (4 threads/row, 16 floats -> bf16) ----
    {
        const int row = tid >> 2;                // 0..63
        const int fo  = (tid & 3) * 4;           // float4 start index
        const bool qside = row < 32;
        const int li = qside ? (q0 + row) : (q0 + row - 32);
        const bool valid = qside ? (do_q && li < nq) : (do_k && li < nk);
        if (valid) {
            int token = qside ? list_q[r * QCAP + li] : list_k[r * QCAP + li];
            int n = token >> 5, t = token & 31;
            const float* src = (t == 0)
                ? (curr_all + n * EE)
                : (msg + ((size_t)n * MM + (t - 1)) * EE);
            float4 f0 = ((const float4*)src)[fo + 0];
            float4 f1 = ((const float4*)src)[fo + 1];
            float4 f2 = ((const float4*)src)[fo + 2];
            float4 f3 = ((const float4*)src)[fo + 3];
            unsigned short b[16] = {
                f2bf(f0.x), f2bf(f0.y), f2bf(f0.z), f2bf(f0.w),
                f2bf(f1.x), f2bf(f1.y), f2bf(f1.z), f2bf(f1.w),
                f2bf(f2.x), f2bf(f2.y), f2bf(f2.z), f2bf(f2.w),
                f2bf(f3.x), f2bf(f3.y), f2bf(f3.z), f2bf(f3.w) };
            unsigned short* d = &x_s[row * WSTR + fo * 4];
            *(short8*)d       = *(short8*)&b[0];
            *(short8*)(d + 8) = *(short8*)&b[8];
        }
    }
    __syncthreads();

    // ---- GEMM A: q and v (wave: mtile = w&1, mat = w>>1) ----
    if (do_q) {
        const int mtile = wave & 1;
        const unsigned short* w_s = (wave >> 1) ? wv_s : wq_s;
        float* outp = (wave >> 1) ? v_all : q_all;
        const int m = mtile * 16 + col;
        f32x4 acc[4] = {{0,0,0,0},{0,0,0,0},{0,0,0,0},{0,0,0,0}};
#pragma unroll
        for (int kk = 0; kk < 2; ++kk) {
            short8 af = *(const short8*)&x_s[m * WSTR + kk * 32 + quad * 8];
#pragma unroll
            for (int nt = 0; nt < 4; ++nt) {
                short8 bf = *(const short8*)&w_s[(nt * 16 + col) * WSTR + kk * 32 + quad * 8];
                acc[nt] = __builtin_amdgcn_mfma_f32_16x16x32_bf16(af, bf, acc[nt], 0, 0, 0);
            }
        }
#pragma unroll
        for (int nt = 0; nt < 4; ++nt)
#pragma unroll
            for (int reg = 0; reg < 4; ++reg) {
                int rrow = mtile * 16 + quad * 4 + reg;
                int token = tq_s[rrow];
                if (token >= 0)
                    outp[(size_t)token * EE + nt * 16 + col] = acc[nt][reg];
            }
    }

    // ---- GEMM B: k (wave: mtile = w&1, n-half = w>>1) ----
    if (do_k) {
        const int mtile = wave & 1;
        const int nh = wave >> 1;
        const int m = 32 + mtile * 16 + col;
        f32x4 acc[2] = {{0,0,0,0},{0,0,0,0}};
#pragma unroll
        for (int kk = 0; kk < 2; ++kk) {
            short8 af = *(const short8*)&x_s[m * WSTR + kk * 32 + quad * 8];
#pragma unroll
            for (int j = 0; j < 2; ++j) {
                int nt = nh * 2 + j;
                short8 bf = *(const short8*)&wk_s[(nt * 16 + col) * WSTR + kk * 32 + quad * 8];
                acc[j] = __builtin_amdgcn_mfma_f32_16x16x32_bf16(af, bf, acc[j], 0, 0, 0);
            }
        }
#pragma unroll
        for (int j = 0; j < 2; ++j)
#pragma unroll
            for (int reg = 0; reg < 4; ++reg) {
                int rrow = mtile * 16 + quad * 4 + reg;
                int token = tk_s[rrow];
                if (token >= 0)
                    k_all[(size_t)token * EE + (nh * 2 + j) * 16 + col] = acc[j][reg];
            }
    }
}

// ---------------------------------------------------------------------------
// attn: one block per node; q/k/v contiguous [32][64] f32 rows.
// ---------------------------------------------------------------------------
__global__ __launch_bounds__(256) void attn_kernel(
    const float* __restrict__ q_all, const float* __restrict__ k_all,
    const float* __restrict__ v_all, const float* __restrict__ ffn_w,
    const float* __restrict__ ffn_b, float* __restrict__ out)
{
    const int n = blockIdx.x, tid = threadIdx.x;
    __shared__ float q_s[TT][68], k_s[TT][68], v_s[TT][68];
    __shared__ float s_s[TT][TT + 1];
    __shared__ float att0[TT];
    __shared__ float pooled[EE];

    {
        const float4* qg = (const float4*)(q_all + (size_t)n * TT * EE);
        const float4* kg = (const float4*)(k_all + (size_t)n * TT * EE);
        const float4* vg = (const float4*)(v_all + (size_t)n * TT * EE);
        for (int i = tid; i < TT * EE / 4; i += 256) {
            int row = i >> 4, c = i & 15;
            ((float4*)&q_s[row][0])[c] = qg[i];
            ((float4*)&k_s[row][0])[c] = kg[i];
            ((float4*)&v_s[row][0])[c] = vg[i];
        }
    }
    __syncthreads();

    {   // scores s[qi][ki] = dot(q[qi],k[ki]) / 8
        const int ki = tid & 31;
        for (int qi = tid >> 5; qi < TT; qi += 8) {
            const float4* qp = (const float4*)&q_s[qi][0];
            const float4* kp = (const float4*)&k_s[ki][0];
            float acc = 0.f;
            for (int e4 = 0; e4 < EE / 4; ++e4) {
                float4 a = qp[e4], b = kp[e4];
                acc += a.x * b.x + a.y * b.y + a.z * b.z + a.w * b.w;
            }
            s_s[qi][ki] = acc * 0.125f;
        }
    }
    __syncthreads();

    // softmax over the QUERY axis per column; only row 0 of att needed
    if (tid < TT) {
        float mx = -INFINITY;
        for (int qi = 0; qi < TT; ++qi) mx = fmaxf(mx, s_s[qi][tid]);
        float sum = 0.f;
        for (int qi = 0; qi < TT; ++qi) sum += __expf(s_s[qi][tid] - mx);
        att0[tid] = __expf(s_s[0][tid] - mx) / sum;
    }
    __syncthreads();

    if (tid < EE) {
        float acc = 0.f;
        for (int ki = 0; ki < TT; ++ki)
            acc = fmaf(att0[ki], v_s[ki][tid], acc);
        pooled[tid] = acc;
    }
    __syncthreads();

    if (tid < EE) {
        float acc = ffn_b[tid];
        for (int a = 0; a < EE; ++a)
            acc = fmaf(pooled[a], ffn_w[a * EE + tid], acc);
        out[n * EE + tid] = acc;
    }
}

extern "C" void kernel_launch(void* const* d_in, const int* in_sizes, int n_in,
                              void* d_out, int out_size, void* d_ws, size_t ws_size,
                              hipStream_t stream) {
    const float* h            = (const float*)d_in[0];
    const float* msg          = (const float*)d_in[1];
    const int*   msg_type     = (const int*)  d_in[2];
    const int*   r_label_node = (const int*)  d_in[3];
    const int*   r_label_msg  = (const int*)  d_in[4];
    const float* W_self       = (const float*)d_in[5];
    const float* Q            = (const float*)d_in[6];
    const float* K            = (const float*)d_in[7];
    const float* V            = (const float*)d_in[8];
    const float* ffn_w        = (const float*)d_in[9];
    const float* ffn_b        = (const float*)d_in[10];
    float*       out          = (float*)d_out;

    // ws layout (all 16B-aligned):
    int* cnt_q  = (int*)d_ws;                          // [200*CPAD]
    int* cnt_k  = cnt_q + NREL * CPAD;                 // [200*CPAD]
    int* list_q = cnt_k + NREL * CPAD;                 // [200*QCAP]
    int* list_k = list_q + NREL * QCAP;                // [200*QCAP]
    unsigned short* wt_q = (unsigned short*)(list_k + NREL * QCAP);  // [201*4096]
    unsigned short* wt_k = wt_q + (size_t)NMAT * EE * EE;
    unsigned short* wt_v = wt_k + (size_t)NMAT * EE * EE;
    float* curr_all = (float*)(wt_v + (size_t)NMAT * EE * EE);
    float* q_all = curr_all + NN * EE;
    float* k_all = q_all + (size_t)NN * TT * EE;
    float* v_all = k_all + (size_t)NN * TT * EE;

    hipMemsetAsync(cnt_q, 0, 2 * NREL * CPAD * sizeof(int), stream);
    prep_convert_kernel<<<3 * NMAT + NN, 256, 0, stream>>>(
        h, W_self, Q, K, V, msg_type, r_label_node, r_label_msg,
        cnt_q, cnt_k, list_q, list_k, wt_q, wt_k, wt_v, curr_all, k_all);
    proj_tile_kernel<<<NREL * NT, 256, 0, stream>>>(
        curr_all, msg, wt_q, wt_k, wt_v, cnt_q, cnt_k, list_q, list_k,
        q_all, k_all, v_all);
    attn_kernel<<<NN, 256, 0, stream>>>(q_all, k_all, v_all, ffn_w, ffn_b, out);
}